// Round 6
// baseline (204.641 us; speedup 1.0000x reference)
//
#include <hip/hip_runtime.h>
#include <cstdint>
#include <math.h>

#define B_   8
#define S_   1024
#define D_   1024
#define NH_  16
#define NKV_ 8
#define HD_  64
#define M_   (B_*S_)   // 8192 tokens

using bf16   = __bf16;
using bf16x4 = __attribute__((ext_vector_type(4))) __bf16;
using bf16x8 = __attribute__((ext_vector_type(8))) __bf16;
using f32x4  = __attribute__((ext_vector_type(4))) float;

// ---------------- async global->LDS, width 16 (m97 idiom) ----------------
__device__ __forceinline__ void gll16(const bf16* g, const bf16* l) {
    __builtin_amdgcn_global_load_lds(
        (const __attribute__((address_space(1))) unsigned int*)(uintptr_t)g,
        (__attribute__((address_space(3))) unsigned int*)(uintptr_t)l,
        16, 0, 0);
}

// Opaque LDS read (attn only -- GEMM uses C++ reads so the compiler emits its
// fine-grained lgkmcnt interleave, which round 5 proved superior).
__device__ __forceinline__ void dsr128(bf16x8& d, const bf16* p) {
    asm volatile("ds_read_b128 %0, %1" : "=v"(d) : "v"((unsigned)(uintptr_t)p));
}
__device__ __forceinline__ void lgkm0() {
    asm volatile("s_waitcnt lgkmcnt(0)" ::: "memory");
    __builtin_amdgcn_sched_barrier(0);
}
__device__ __forceinline__ void vm_wait0()  { asm volatile("s_waitcnt vmcnt(0)"  ::: "memory"); }
__device__ __forceinline__ void vm_wait4()  { asm volatile("s_waitcnt vmcnt(4)"  ::: "memory"); }
__device__ __forceinline__ void vm_wait6()  { asm volatile("s_waitcnt vmcnt(6)"  ::: "memory"); }
__device__ __forceinline__ void vm_wait8()  { asm volatile("s_waitcnt vmcnt(8)"  ::: "memory"); }
__device__ __forceinline__ void bar()       { __builtin_amdgcn_s_barrier(); asm volatile("" ::: "memory"); }

// ---------------- fused prep1: f32->bf16 cvt (blocks 0..8191) + weight transposes ----------------
__global__ void k_prep1(const float* __restrict__ x,
                        const float* __restrict__ wq, const float* __restrict__ wk,
                        const float* __restrict__ wv, const float* __restrict__ wo,
                        bf16* __restrict__ xb, bf16* __restrict__ wqkvT, bf16* __restrict__ woT) {
    __shared__ float tile[64 * 65];
    int bid = blockIdx.x;
    int t = threadIdx.x;
    if (bid < 8192) {                       // cvt: 8192*256 threads cover M_*D_/4 exactly
        int i = bid * 256 + t;
        float4 v = ((const float4*)x)[i];
        bf16x4 o = { (bf16)v.x, (bf16)v.y, (bf16)v.z, (bf16)v.w };
        ((bf16x4*)xb)[i] = o;
        return;
    }
    int b2 = bid - 8192;                    // 0..767 transpose tiles
    int bx = b2 % 48, by = b2 / 48;
    const int R = 1024;
    const float* in; bf16* out; int C, xo;
    if (bx < 16)      { in = wq; out = wqkvT;               C = 1024; xo = bx; }
    else if (bx < 24) { in = wk; out = wqkvT + 1024 * 1024; C = 512;  xo = bx - 16; }
    else if (bx < 32) { in = wv; out = wqkvT + 1536 * 1024; C = 512;  xo = bx - 24; }
    else              { in = wo; out = woT;                 C = 1024; xo = bx - 32; }
    int r0 = by * 64, c0 = xo * 64;
    #pragma unroll
    for (int it = 0; it < 16; ++it) {
        int idx = it * 256 + t;
        int r = idx >> 6, c = idx & 63;
        tile[r * 65 + c] = in[(size_t)(r0 + r) * C + c0 + c];
    }
    __syncthreads();
    #pragma unroll
    for (int it = 0; it < 16; ++it) {
        int idx = it * 256 + t;
        int c = idx >> 6, r = idx & 63;
        out[(size_t)(c0 + c) * R + r0 + r] = (bf16)tile[r * 65 + c];
    }
}

// ---------------- reuse-optimal GEMM: per-wave 128x(NFR*16), BK=32, triple-buffer ----------------
// The round-0..5 lesson: every schedule with per-wave 128x64 / 64x64 output hit the
// SAME ~30% MfmaUtil -- the binding constraint is LDS bytes per MFMA (384-512 B),
// not the sync schedule. This kernel cuts it to 256 B/MFMA (NFR=8): 4 waves (1 per
// SIMD), per-wave 128x128, acc[8][8] (256 VGPR), 16 ds_read_b128 + 64 MFMA per
// BK=32 step. Triple-buffered LDS (96/72 KB) + one barrier + one counted vmcnt per
// step: stage(T+2) is issued every step and the wait allows it to stay in flight
// (never drains). No internal barriers -> the compiler software-pipelines ds_reads
// against MFMAs with fine-grained lgkmcnt (m97-verified behavior). 1 wave/SIMD also
// removes the barrier-lockstep phase serialization of the 8-wave variants.
template <typename OutT, int NFR>   // NFR: n-frags per wave. 8 -> BN=256, 4 -> BN=128
__global__ __launch_bounds__(256, 1) void k_gemmW(const bf16* __restrict__ A,
                                                  const bf16* __restrict__ Bt,
                                                  OutT* __restrict__ C, int M, int N, int K) {
    constexpr int BN = NFR * 32;           // 2 waves along N
    __shared__ __align__(16) bf16 aL3[3 * 256 * 32];   // 48 KB
    __shared__ __align__(16) bf16 bL3[3 * BN * 32];    // 48 / 24 KB
    const int t    = threadIdx.x;
    const int lane = t & 63;
    const int w    = t >> 6;
    const int quad = lane >> 4;
    const int l16  = lane & 15;
    const int wr   = w >> 1;               // 0..1  (M half)
    const int wc   = w & 1;                // 0..1  (N half)

    // XCD swizzle (nwg = 256, divisible by 8)
    int bid = blockIdx.y * gridDim.x + blockIdx.x;
    int cpx = (gridDim.x * gridDim.y) >> 3;
    int sw  = (bid & 7) * cpx + (bid >> 3);
    int bx  = sw % gridDim.x, by = sw / gridDim.x;
    const int m0 = by * 256;
    const int n0 = bx * BN;

    f32x4 acc[8][NFR] = {};

    // swizzle: octet slot c of row r holds global octet c ^ ((r&3)^((r>>2)&3)).
    // Involution (XOR) -> same function at stage and read. Spreads the 16-lane
    // column-read across bank groups (2-way residual aliasing is free, m136).
    auto stage = [&](int kb, int sb) {
        const int k0 = kb << 5;
        #pragma unroll
        for (int it = 0; it < 4; ++it) {   // A: 256 rows x 4 octets / 256 thr
            int u = it * 256 + t;
            int r = u >> 2, c = u & 3;
            int cg = c ^ ((r & 3) ^ ((r >> 2) & 3));
            gll16(A + (size_t)(m0 + r) * K + k0 + cg * 8, aL3 + sb * (256 * 32) + u * 8);
        }
        #pragma unroll
        for (int it = 0; it < BN / 64; ++it) {  // B: BN rows x 4 octets / 256 thr
            int u = it * 256 + t;
            int r = u >> 2, c = u & 3;
            int cg = c ^ ((r & 3) ^ ((r >> 2) & 3));
            gll16(Bt + (size_t)(n0 + r) * K + k0 + cg * 8, bL3 + sb * (BN * 32) + u * 8);
        }
    };

    const int NT = K >> 5;                 // 32 for K=1024

    stage(0, 0);
    stage(1, 1);

    int cur = 0;
    for (int T = 0; T < NT; ++T) {
        // counted wait: only stage(T+1)'s loads may remain in flight -> buffer cur
        // (tile T, staged two steps ago) is complete; queue never drains mid-loop.
        if (T + 1 < NT) { if constexpr (NFR == 8) vm_wait8(); else vm_wait6(); }
        else vm_wait0();
        bar();                             // publish tile T; closes readers of stg

        const bf16* aT = aL3 + cur * (256 * 32);
        const bf16* bT = bL3 + cur * (BN * 32);
        bf16x8 af[8], bf[NFR];
        #pragma unroll
        for (int mi = 0; mi < 8; ++mi) {
            int row = wr * 128 + mi * 16 + l16;
            int ch  = quad ^ ((row & 3) ^ ((row >> 2) & 3));
            af[mi] = *(const bf16x8*)&aT[row * 32 + ch * 8];
        }
        #pragma unroll
        for (int ni = 0; ni < NFR; ++ni) {
            int row = wc * (NFR * 16) + ni * 16 + l16;
            int ch  = quad ^ ((row & 3) ^ ((row >> 2) & 3));
            bf[ni] = *(const bf16x8*)&bT[row * 32 + ch * 8];
        }

        int stg = cur + 2; if (stg >= 3) stg -= 3;     // = (T+2)%3, read at T-1 -> freed at bar
        if (T + 2 < NT) stage(T + 2, stg);

        #pragma unroll
        for (int mi = 0; mi < 8; ++mi)
            #pragma unroll
            for (int ni = 0; ni < NFR; ++ni)
                acc[mi][ni] = __builtin_amdgcn_mfma_f32_16x16x32_bf16(af[mi], bf[ni], acc[mi][ni], 0, 0, 0);

        cur = (cur == 2) ? 0 : cur + 1;
    }

    #pragma unroll
    for (int mi = 0; mi < 8; ++mi)
        #pragma unroll
        for (int ni = 0; ni < NFR; ++ni)
            #pragma unroll
            for (int r = 0; r < 4; ++r) {
                int row = m0 + wr * 128 + mi * 16 + quad * 4 + r;   // C/D: row = quad*4+reg
                int col = n0 + wc * (NFR * 16) + ni * 16 + l16;     //      col = lane&15
                C[(size_t)row * N + col] = (OutT)acc[mi][ni][r];
            }
}

// ---------------- fused prep2: RoPE scatter (blocks 0..8191) + V transpose ----------------
__global__ void k_prep2(const bf16* __restrict__ qkv, const float* __restrict__ cosg,
                        const float* __restrict__ sing, bf16* __restrict__ qd,
                        bf16* __restrict__ kd, bf16* __restrict__ vt) {
    __shared__ __align__(16) bf16 tile[64 * 72];
    int bid = blockIdx.x;
    int t = threadIdx.x;
    if (bid < 8192) {                       // RoPE: 192 active lanes/token
        if (t < 192) {
            int token = bid;
            int b = token >> 10, s = token & 1023;
            int hh = t >> 3, i8 = t & 7;
            float4 c4 = *(const float4*)&cosg[s * 32 + i8 * 4];
            float4 s4 = *(const float4*)&sing[s * 32 + i8 * 4];
            int srcBase, dstBase;
            bf16* dst;
            float sf;
            if (hh < 16) {
                srcBase = token * 2048 + hh * 64;
                dstBase = ((b * NH_ + hh) * S_ + s) * 64;
                dst = qd;
                sf = 0.180336879f;          // 0.125 * log2(e) folded into Q
            } else {
                int h = hh - 16;
                srcBase = token * 2048 + 1024 + h * 64;
                dstBase = ((b * NKV_ + h) * S_ + s) * 64;
                dst = kd;
                sf = 1.0f;
            }
            bf16x8 v = *(const bf16x8*)&qkv[srcBase + i8 * 8];
            const float cc[4] = { c4.x, c4.y, c4.z, c4.w };
            const float ss[4] = { s4.x, s4.y, s4.z, s4.w };
            bf16x8 o;
            #pragma unroll
            for (int j = 0; j < 4; ++j) {
                float e  = (float)v[2 * j];
                float od = (float)v[2 * j + 1];
                o[2 * j]     = (bf16)(sf * (e * cc[j] - od * ss[j]));
                o[2 * j + 1] = (bf16)(sf * (e * ss[j] + od * cc[j]));
            }
            *(bf16x8*)&dst[dstBase + i8 * 8] = o;
        }
        return;
    }
    int b2 = bid - 8192;                    // 0..1023 vtrans tiles
    int st = b2 & 15;
    int h  = (b2 >> 4) & 7;
    int b  = b2 >> 7;
    int s0 = st * 64;
    #pragma unroll
    for (int it = 0; it < 2; ++it) {
        int ci = it * 256 + t;
        int r = ci >> 3, c = ci & 7;           // r = s, c = d-chunk
        *(uint4*)&tile[r * 72 + c * 8] =
            *(const uint4*)&qkv[(size_t)(b * S_ + s0 + r) * 2048 + 1536 + h * 64 + c * 8];
    }
    __syncthreads();
    #pragma unroll
    for (int it = 0; it < 2; ++it) {
        int ci = it * 256 + t;
        int d = ci >> 3, sc = ci & 7;
        int g = sc >> 2, q4 = sc & 3;          // internal chunk -> (32-group, quad)
        bf16x8 v;
        #pragma unroll
        for (int j = 0; j < 8; ++j) {
            int s_ext = g * 32 + q4 * 4 + (j & 3) + 16 * (j >> 2);
            v[j] = tile[s_ext * 72 + d];
        }
        *(bf16x8*)&vt[(size_t)((b * NKV_ + h) * 64 + d) * S_ + s0 + sc * 8] = v;
    }
}

// ---------------- flash attention (unchanged from round 5 -- it improved there) ----------------
__global__ __launch_bounds__(256, 4) void k_attn(const bf16* __restrict__ q, const bf16* __restrict__ k,
                                                 const bf16* __restrict__ vt, bf16* __restrict__ out) {
    __shared__ __align__(16) bf16 kt[2 * 64 * 64];
    __shared__ __align__(16) bf16 vtt[2 * 64 * 64];
    int bid = blockIdx.x;
    int qt = 15 - (bid >> 7);               // big q-tiles first
    int combo = bid & 127;
    int b = combo >> 4, h = combo & 15;
    int hkv = h >> 1;                       // jnp.repeat: q-head h -> kv head h/2
    int t = threadIdx.x;
    int w = t >> 6, lane = t & 63, quad = lane >> 4, l16 = lane & 15;

    const bf16* qh = q + (size_t)(b * NH_ + h) * S_ * 64;
    int qw = qt * 64 + w * 16;
    const bf16* qb = qh + (size_t)(qw + l16) * 64;
    bf16x8 qf0 = *(const bf16x8*)(qb + quad * 8);
    bf16x8 qf1 = *(const bf16x8*)(qb + 32 + quad * 8);

    const bf16* kg = k  + (size_t)(b * NKV_ + hkv) * S_ * 64;
    const bf16* vg = vt + (size_t)(b * NKV_ + hkv) * 64 * S_;

    const int sr0 = t >> 3;                 // staging row 0..31 (+32 for it=1)
    const int cs  = t & 7;                  // staging swizzled chunk slot

    auto stage = [&](int u, int buf) {
        int k0 = u * 64;
        #pragma unroll
        for (int it = 0; it < 2; ++it) {
            int r  = sr0 + it * 32;
            int cg = cs ^ (r & 7);          // slot cs holds global chunk cs^(r&7)
            int ci = it * 256 + t;
            gll16(kg + (size_t)(k0 + r) * 64 + cg * 8, kt  + buf * 4096 + ci * 8);
            gll16(vg + (size_t)r * S_ + k0 + cg * 8,   vtt + buf * 4096 + ci * 8);
        }
    };

    const bf16 one = (bf16)1.0f;
    const bf16x8 vones = { one, one, one, one, one, one, one, one };

    f32x4 o[4] = {};        // PV C-layout: row q=quad*4+r, col d=dc*16+l16
    f32x4 ol = {};          // ones-column: ol[r] = row-sum of P for q=quad*4+r
    const int klim = ((qw + l16) & ~7) + 8; // block-causal, BLK=8

    auto unit = [&](const bf16* ktb, const bf16* vtb, int k0, bool diag) {
        bf16x8 af[8];
        #pragma unroll
        for (int kk = 0; kk < 2; ++kk)
            #pragma unroll
            for (int f = 0; f < 4; ++f) {
                int row = f * 16 + l16;
                int ch  = (kk * 4 + quad) ^ (row & 7);
                dsr128(af[kk * 4 + f], &ktb[row * 64 + ch * 8]);
            }
        lgkm0();
        f32x4 sc[4] = {};
        __builtin_amdgcn_s_setprio(1);
        #pragma unroll
        for (int kk = 0; kk < 2; ++kk)
            #pragma unroll
            for (int f = 0; f < 4; ++f)
                sc[f] = __builtin_amdgcn_mfma_f32_16x16x32_bf16(af[kk * 4 + f], kk ? qf1 : qf0, sc[f], 0, 0, 0);
        __builtin_amdgcn_s_setprio(0);

        bf16x8 vbf[8];
        #pragma unroll
        for (int dc = 0; dc < 4; ++dc)
            #pragma unroll
            for (int kk = 0; kk < 2; ++kk) {
                int row = dc * 16 + l16;
                int ch  = (kk * 4 + quad) ^ (row & 7);
                dsr128(vbf[dc * 2 + kk], &vtb[row * 64 + ch * 8]);
            }

        float p[4][4];
        #pragma unroll
        for (int f = 0; f < 4; ++f)
            #pragma unroll
            for (int r = 0; r < 4; ++r) {
                float pv = __builtin_amdgcn_exp2f(sc[f][r]);
                if (diag && (k0 + f * 16 + quad * 4 + r >= klim)) pv = 0.f;
                p[f][r] = pv;
            }
        bf16x8 pa0, pa1;
        #pragma unroll
        for (int j = 0; j < 4; ++j) {
            pa0[j]     = (bf16)p[0][j];
            pa0[j + 4] = (bf16)p[1][j];
            pa1[j]     = (bf16)p[2][j];
            pa1[j + 4] = (bf16)p[3][j];
        }
        ol = __builtin_amdgcn_mfma_f32_16x16x32_bf16(pa0, vones, ol, 0, 0, 0);
        ol = __builtin_amdgcn_mfma_f32_16x16x32_bf16(pa1, vones, ol, 0, 0, 0);

        lgkm0();
        __builtin_amdgcn_s_setprio(1);
        #pragma unroll
        for (int dc = 0; dc < 4; ++dc)
            #pragma unroll
            for (int kk = 0; kk < 2; ++kk)
                o[dc] = __builtin_amdgcn_mfma_f32_16x16x32_bf16(kk ? pa1 : pa0, vbf[dc * 2 + kk], o[dc], 0, 0, 0);
        __builtin_amdgcn_s_setprio(0);
    };

    const int NU = qt + 1;
    stage(0, 0);
    asm volatile("" :: "v"(qf0), "v"(qf1));

    int u = 0;
    for (; u + 2 <= NU; u += 2) {
        bar();                              // close readers of buf1 (unit u-1)
        stage(u + 1, 1);
        vm_wait4();                         // stage(u) landed; stage(u+1) in flight
        bar();                              // publish buf0
        unit(kt, vtt, u * 64, false);       // u <= NU-2: never diagonal
        bar();                              // close readers of buf0
        bool hn = (u + 2 < NU);
        if (hn) { stage(u + 2, 0); vm_wait4(); } else vm_wait0();
        bar();                              // publish buf1
        unit(kt + 4096, vtt + 4096, (u + 1) * 64, (u + 1) == NU - 1);
    }
    if (u < NU) {                           // odd-NU tail: diagonal unit, buf0
        bar();
        vm_wait0();
        bar();
        unit(kt, vtt, u * 64, true);
    }

    // epilogue
    #pragma unroll
    for (int r = 0; r < 4; ++r) {
        float invl = 1.0f / ol[r];
        #pragma unroll
        for (int dc = 0; dc < 4; ++dc) {
            int row = qw + quad * 4 + r;
            int col = h * 64 + dc * 16 + l16;
            out[(size_t)(b * S_ + row) * 1024 + col] = (bf16)(o[dc][r] * invl);
        }
    }
}

// ---------------- launch ----------------
extern "C" void kernel_launch(void* const* d_in, const int* in_sizes, int n_in,
                              void* d_out, int out_size, void* d_ws, size_t ws_size,
                              hipStream_t stream) {
    const float* x  = (const float*)d_in[0];
    const float* wq = (const float*)d_in[1];
    const float* wk = (const float*)d_in[2];
    const float* wv = (const float*)d_in[3];
    const float* wo = (const float*)d_in[4];
    const float* fc = (const float*)d_in[5];
    const float* fs = (const float*)d_in[6];
    (void)in_sizes; (void)n_in; (void)out_size; (void)ws_size;

    char* ws = (char*)d_ws;
    bf16* xb    = (bf16*)(ws);                          // 16 MB, reused as q after GEMM1
    bf16* wqkvT = (bf16*)(ws + (16u << 20));            //  4 MB  [2048][1024]
    bf16* woT   = (bf16*)(ws + (20u << 20));            //  2 MB  [1024][1024]
    bf16* qkvb  = (bf16*)(ws + (22u << 20));            // 32 MB  [8192][2048], reused as attn out
    bf16* kb    = (bf16*)(ws + (54u << 20));            //  8 MB  [8][8][1024][64]
    bf16* vtb   = (bf16*)(ws + (62u << 20));            //  8 MB  [8][8][64][1024]  (70 MB total)
    bf16* qb    = xb;
    bf16* attnb = qkvb;

    k_prep1<<<dim3(8960), dim3(256), 0, stream>>>(x, wq, wk, wv, wo, xb, wqkvT, woT);

    // GEMM1: [8192,1024] x [2048,1024]^T -> 256x256 tiles, grid 8x32 = 256 wgs (1/CU)
    k_gemmW<bf16, 8><<<dim3(8, 32), dim3(256), 0, stream>>>(xb, wqkvT, qkvb, M_, 2048, 1024);

    k_prep2<<<dim3(9216), dim3(256), 0, stream>>>(qkvb, fc, fs, qb, kb, vtb);

    // attn: per-q-tile blocks, 2048 wgs, big tiles first
    k_attn<<<dim3(2048), dim3(256), 0, stream>>>(qb, kb, vtb, attnb);

    // GEMM2: [8192,1024] x [1024,1024]^T -> 256x128 tiles, grid 8x32 = 256 wgs (1/CU)
    k_gemmW<float, 4><<<dim3(8, 32), dim3(256), 0, stream>>>(attnb, woT, (float*)d_out, M_, 1024, 1024);
}

// Round 7
// 190.882 us; speedup vs baseline: 1.0721x; 1.0721x over previous
//
#include <hip/hip_runtime.h>
#include <cstdint>
#include <math.h>

#define B_   8
#define S_   1024
#define D_   1024
#define NH_  16
#define NKV_ 8
#define HD_  64
#define M_   (B_*S_)   // 8192 tokens

using bf16   = __bf16;
using bf16x4 = __attribute__((ext_vector_type(4))) __bf16;
using bf16x8 = __attribute__((ext_vector_type(8))) __bf16;
using f32x4  = __attribute__((ext_vector_type(4))) float;

// ---------------- async global->LDS, width 16 (m97 idiom) ----------------
__device__ __forceinline__ void gll16(const bf16* g, const bf16* l) {
    __builtin_amdgcn_global_load_lds(
        (const __attribute__((address_space(1))) unsigned int*)(uintptr_t)g,
        (__attribute__((address_space(3))) unsigned int*)(uintptr_t)l,
        16, 0, 0);
}

// Opaque LDS read (attn only)
__device__ __forceinline__ void dsr128(bf16x8& d, const bf16* p) {
    asm volatile("ds_read_b128 %0, %1" : "=v"(d) : "v"((unsigned)(uintptr_t)p));
}
__device__ __forceinline__ void lgkm0() {
    asm volatile("s_waitcnt lgkmcnt(0)" ::: "memory");
    __builtin_amdgcn_sched_barrier(0);
}
__device__ __forceinline__ void vm_wait0()  { asm volatile("s_waitcnt vmcnt(0)"  ::: "memory"); }
__device__ __forceinline__ void vm_wait4()  { asm volatile("s_waitcnt vmcnt(4)"  ::: "memory"); }
__device__ __forceinline__ void vm_wait8()  { asm volatile("s_waitcnt vmcnt(8)"  ::: "memory"); }
__device__ __forceinline__ void bar()       { __builtin_amdgcn_s_barrier(); asm volatile("" ::: "memory"); }

// ---------------- fused prep1: f32->bf16 cvt (blocks 0..8191) + weight transposes ----------------
__global__ void k_prep1(const float* __restrict__ x,
                        const float* __restrict__ wq, const float* __restrict__ wk,
                        const float* __restrict__ wv, const float* __restrict__ wo,
                        bf16* __restrict__ xb, bf16* __restrict__ wqkvT, bf16* __restrict__ woT) {
    __shared__ float tile[64 * 65];
    int bid = blockIdx.x;
    int t = threadIdx.x;
    if (bid < 8192) {                       // cvt: 8192*256 threads cover M_*D_/4 exactly
        int i = bid * 256 + t;
        float4 v = ((const float4*)x)[i];
        bf16x4 o = { (bf16)v.x, (bf16)v.y, (bf16)v.z, (bf16)v.w };
        ((bf16x4*)xb)[i] = o;
        return;
    }
    int b2 = bid - 8192;                    // 0..767 transpose tiles
    int bx = b2 % 48, by = b2 / 48;
    const int R = 1024;
    const float* in; bf16* out; int C, xo;
    if (bx < 16)      { in = wq; out = wqkvT;               C = 1024; xo = bx; }
    else if (bx < 24) { in = wk; out = wqkvT + 1024 * 1024; C = 512;  xo = bx - 16; }
    else if (bx < 32) { in = wv; out = wqkvT + 1536 * 1024; C = 512;  xo = bx - 24; }
    else              { in = wo; out = woT;                 C = 1024; xo = bx - 32; }
    int r0 = by * 64, c0 = xo * 64;
    #pragma unroll
    for (int it = 0; it < 16; ++it) {
        int idx = it * 256 + t;
        int r = idx >> 6, c = idx & 63;
        tile[r * 65 + c] = in[(size_t)(r0 + r) * C + c0 + c];
    }
    __syncthreads();
    #pragma unroll
    for (int it = 0; it < 16; ++it) {
        int idx = it * 256 + t;
        int c = idx >> 6, r = idx & 63;
        out[(size_t)(c0 + c) * R + r0 + r] = (bf16)tile[r * 65 + c];
    }
}

// ---------------- 128x128 GEMM, dbuf + counted vmcnt + 2 blocks/CU ----------------
// Rounds 0-6 lesson: every 256-tile schedule ran 1 block/CU and pinned at ~30%
// MfmaUtil -- prologue fill, 128KB C-write epilogue, and every barrier gap had
// nothing else to run on the CU. This config pairs a never-drain counted pipeline
// with block-level TLP: 128^2 tile, BK=64, 4 waves (per-wave 64x64), dbuf 64 KB
// -> 2 blocks/CU. Per tile: {stage(T+1 -> alt buf) (8 gll16/thread); vmcnt(8)
// [T's 8 loads issued a FULL TILE ago -> free; T+1's 8 stay in flight]; bar;
// 16 ds_read_b128 + 32 MFMA (C++ reads: compiler emits fine-grained lgkmcnt
// interleave, which r4-vs-r5 proved beats manual lgkm0 drains); bar}. One
// barrier-pair per tile. Verified BK=64 XOR chunk swizzle (0 conflicts, r4/r5).
template <typename OutT>
__global__ __launch_bounds__(256, 2) void k_gemm128(const bf16* __restrict__ A,
                                                    const bf16* __restrict__ Bt,
                                                    OutT* __restrict__ C, int M, int N, int K) {
    __shared__ __align__(16) bf16 aL2[2 * 128 * 64];   // 32 KB
    __shared__ __align__(16) bf16 bL2[2 * 128 * 64];   // 32 KB
    const int t    = threadIdx.x;
    const int lane = t & 63;
    const int w    = t >> 6;
    const int quad = lane >> 4;
    const int l16  = lane & 15;
    const int wr   = w >> 1;               // 0..1 (M half)
    const int wc   = w & 1;                // 0..1 (N half)

    // XCD swizzle (nwg divisible by 8)
    int bid = blockIdx.y * gridDim.x + blockIdx.x;
    int cpx = (gridDim.x * gridDim.y) >> 3;
    int sw  = (bid & 7) * cpx + (bid >> 3);
    int bx  = sw % gridDim.x, by = sw / gridDim.x;
    const int m0 = by * 128;
    const int n0 = bx * 128;

    f32x4 acc[4][4] = {};

    auto stage = [&](int kb, int sb) {     // 8 gll16/thread: A 4 + B 4
        const int k0 = kb << 6;
        #pragma unroll
        for (int it = 0; it < 4; ++it) {   // A: 128 rows x 8 chunks = 1024 / 256thr
            int ci = it * 256 + t;
            int r = ci >> 3, c = ci & 7;
            int cg = c ^ (r & 7);          // slot c of row r holds global chunk c^(r&7)
            gll16(A + (size_t)(m0 + r) * K + k0 + cg * 8, aL2 + sb * 8192 + ci * 8);
        }
        #pragma unroll
        for (int it = 0; it < 4; ++it) {   // B: 128 rows x 8 chunks
            int ci = it * 256 + t;
            int r = ci >> 3, c = ci & 7;
            int cg = c ^ (r & 7);
            gll16(Bt + (size_t)(n0 + r) * K + k0 + cg * 8, bL2 + sb * 8192 + ci * 8);
        }
    };

    const int NT = K >> 6;                 // 16 for K=1024

    auto tileStep = [&](int T, int buf) {
        if (T + 1 < NT) { stage(T + 1, buf ^ 1); vm_wait8(); }
        else vm_wait0();
        bar();                             // publish tile T (loads issued at T-1)
        const bf16* aL = aL2 + buf * 8192;
        const bf16* bL = bL2 + buf * 8192;
        #pragma unroll
        for (int kk = 0; kk < 2; ++kk) {
            bf16x8 af[4], bfr[4];
            #pragma unroll
            for (int mi = 0; mi < 4; ++mi) {
                int row = wr * 64 + mi * 16 + l16;
                int ch  = (kk * 4 + quad) ^ (row & 7);
                af[mi] = *(const bf16x8*)&aL[row * 64 + ch * 8];
            }
            #pragma unroll
            for (int ni = 0; ni < 4; ++ni) {
                int row = wc * 64 + ni * 16 + l16;
                int ch  = (kk * 4 + quad) ^ (row & 7);
                bfr[ni] = *(const bf16x8*)&bL[row * 64 + ch * 8];
            }
            __builtin_amdgcn_s_setprio(1);
            #pragma unroll
            for (int mi = 0; mi < 4; ++mi)
                #pragma unroll
                for (int ni = 0; ni < 4; ++ni)
                    acc[mi][ni] = __builtin_amdgcn_mfma_f32_16x16x32_bf16(af[mi], bfr[ni], acc[mi][ni], 0, 0, 0);
            __builtin_amdgcn_s_setprio(0);
        }
        bar();                             // close readers of buf before T+1 stages into it
    };

    stage(0, 0);
    for (int T = 0; T < NT; T += 2) {      // literal buffer indices
        tileStep(T, 0);
        tileStep(T + 1, 1);
    }

    #pragma unroll
    for (int mi = 0; mi < 4; ++mi)
        #pragma unroll
        for (int ni = 0; ni < 4; ++ni)
            #pragma unroll
            for (int r = 0; r < 4; ++r) {
                int row = m0 + wr * 64 + mi * 16 + quad * 4 + r;    // C/D: row = quad*4+reg
                int col = n0 + wc * 64 + ni * 16 + l16;             //      col = lane&15
                C[(size_t)row * N + col] = (OutT)acc[mi][ni][r];
            }
}

// ---------------- fused prep2: RoPE scatter (blocks 0..8191) + V transpose ----------------
__global__ void k_prep2(const bf16* __restrict__ qkv, const float* __restrict__ cosg,
                        const float* __restrict__ sing, bf16* __restrict__ qd,
                        bf16* __restrict__ kd, bf16* __restrict__ vt) {
    __shared__ __align__(16) bf16 tile[64 * 72];
    int bid = blockIdx.x;
    int t = threadIdx.x;
    if (bid < 8192) {                       // RoPE: 192 active lanes/token
        if (t < 192) {
            int token = bid;
            int b = token >> 10, s = token & 1023;
            int hh = t >> 3, i8 = t & 7;
            float4 c4 = *(const float4*)&cosg[s * 32 + i8 * 4];
            float4 s4 = *(const float4*)&sing[s * 32 + i8 * 4];
            int srcBase, dstBase;
            bf16* dst;
            float sf;
            if (hh < 16) {
                srcBase = token * 2048 + hh * 64;
                dstBase = ((b * NH_ + hh) * S_ + s) * 64;
                dst = qd;
                sf = 0.180336879f;          // 0.125 * log2(e) folded into Q
            } else {
                int h = hh - 16;
                srcBase = token * 2048 + 1024 + h * 64;
                dstBase = ((b * NKV_ + h) * S_ + s) * 64;
                dst = kd;
                sf = 1.0f;
            }
            bf16x8 v = *(const bf16x8*)&qkv[srcBase + i8 * 8];
            const float cc[4] = { c4.x, c4.y, c4.z, c4.w };
            const float ss[4] = { s4.x, s4.y, s4.z, s4.w };
            bf16x8 o;
            #pragma unroll
            for (int j = 0; j < 4; ++j) {
                float e  = (float)v[2 * j];
                float od = (float)v[2 * j + 1];
                o[2 * j]     = (bf16)(sf * (e * cc[j] - od * ss[j]));
                o[2 * j + 1] = (bf16)(sf * (e * ss[j] + od * cc[j]));
            }
            *(bf16x8*)&dst[dstBase + i8 * 8] = o;
        }
        return;
    }
    int b2 = bid - 8192;                    // 0..1023 vtrans tiles
    int st = b2 & 15;
    int h  = (b2 >> 4) & 7;
    int b  = b2 >> 7;
    int s0 = st * 64;
    #pragma unroll
    for (int it = 0; it < 2; ++it) {
        int ci = it * 256 + t;
        int r = ci >> 3, c = ci & 7;           // r = s, c = d-chunk
        *(uint4*)&tile[r * 72 + c * 8] =
            *(const uint4*)&qkv[(size_t)(b * S_ + s0 + r) * 2048 + 1536 + h * 64 + c * 8];
    }
    __syncthreads();
    #pragma unroll
    for (int it = 0; it < 2; ++it) {
        int ci = it * 256 + t;
        int d = ci >> 3, sc = ci & 7;
        int g = sc >> 2, q4 = sc & 3;          // internal chunk -> (32-group, quad)
        bf16x8 v;
        #pragma unroll
        for (int j = 0; j < 8; ++j) {
            int s_ext = g * 32 + q4 * 4 + (j & 3) + 16 * (j >> 2);
            v[j] = tile[s_ext * 72 + d];
        }
        *(bf16x8*)&vt[(size_t)((b * NKV_ + h) * 64 + d) * S_ + s0 + sc * 8] = v;
    }
}

// ---------------- flash attention (unchanged from round 5 -- best measured) ----------------
__global__ __launch_bounds__(256, 4) void k_attn(const bf16* __restrict__ q, const bf16* __restrict__ k,
                                                 const bf16* __restrict__ vt, bf16* __restrict__ out) {
    __shared__ __align__(16) bf16 kt[2 * 64 * 64];
    __shared__ __align__(16) bf16 vtt[2 * 64 * 64];
    int bid = blockIdx.x;
    int qt = 15 - (bid >> 7);               // big q-tiles first
    int combo = bid & 127;
    int b = combo >> 4, h = combo & 15;
    int hkv = h >> 1;                       // jnp.repeat: q-head h -> kv head h/2
    int t = threadIdx.x;
    int w = t >> 6, lane = t & 63, quad = lane >> 4, l16 = lane & 15;

    const bf16* qh = q + (size_t)(b * NH_ + h) * S_ * 64;
    int qw = qt * 64 + w * 16;
    const bf16* qb = qh + (size_t)(qw + l16) * 64;
    bf16x8 qf0 = *(const bf16x8*)(qb + quad * 8);
    bf16x8 qf1 = *(const bf16x8*)(qb + 32 + quad * 8);

    const bf16* kg = k  + (size_t)(b * NKV_ + hkv) * S_ * 64;
    const bf16* vg = vt + (size_t)(b * NKV_ + hkv) * 64 * S_;

    const int sr0 = t >> 3;                 // staging row 0..31 (+32 for it=1)
    const int cs  = t & 7;                  // staging swizzled chunk slot

    auto stage = [&](int u, int buf) {
        int k0 = u * 64;
        #pragma unroll
        for (int it = 0; it < 2; ++it) {
            int r  = sr0 + it * 32;
            int cg = cs ^ (r & 7);          // slot cs holds global chunk cs^(r&7)
            int ci = it * 256 + t;
            gll16(kg + (size_t)(k0 + r) * 64 + cg * 8, kt  + buf * 4096 + ci * 8);
            gll16(vg + (size_t)r * S_ + k0 + cg * 8,   vtt + buf * 4096 + ci * 8);
        }
    };

    const bf16 one = (bf16)1.0f;
    const bf16x8 vones = { one, one, one, one, one, one, one, one };

    f32x4 o[4] = {};        // PV C-layout: row q=quad*4+r, col d=dc*16+l16
    f32x4 ol = {};          // ones-column: ol[r] = row-sum of P for q=quad*4+r
    const int klim = ((qw + l16) & ~7) + 8; // block-causal, BLK=8

    auto unit = [&](const bf16* ktb, const bf16* vtb, int k0, bool diag) {
        bf16x8 af[8];
        #pragma unroll
        for (int kk = 0; kk < 2; ++kk)
            #pragma unroll
            for (int f = 0; f < 4; ++f) {
                int row = f * 16 + l16;
                int ch  = (kk * 4 + quad) ^ (row & 7);
                dsr128(af[kk * 4 + f], &ktb[row * 64 + ch * 8]);
            }
        lgkm0();
        f32x4 sc[4] = {};
        __builtin_amdgcn_s_setprio(1);
        #pragma unroll
        for (int kk = 0; kk < 2; ++kk)
            #pragma unroll
            for (int f = 0; f < 4; ++f)
                sc[f] = __builtin_amdgcn_mfma_f32_16x16x32_bf16(af[kk * 4 + f], kk ? qf1 : qf0, sc[f], 0, 0, 0);
        __builtin_amdgcn_s_setprio(0);

        bf16x8 vbf[8];
        #pragma unroll
        for (int dc = 0; dc < 4; ++dc)
            #pragma unroll
            for (int kk = 0; kk < 2; ++kk) {
                int row = dc * 16 + l16;
                int ch  = (kk * 4 + quad) ^ (row & 7);
                dsr128(vbf[dc * 2 + kk], &vtb[row * 64 + ch * 8]);
            }

        float p[4][4];
        #pragma unroll
        for (int f = 0; f < 4; ++f)
            #pragma unroll
            for (int r = 0; r < 4; ++r) {
                float pv = __builtin_amdgcn_exp2f(sc[f][r]);
                if (diag && (k0 + f * 16 + quad * 4 + r >= klim)) pv = 0.f;
                p[f][r] = pv;
            }
        bf16x8 pa0, pa1;
        #pragma unroll
        for (int j = 0; j < 4; ++j) {
            pa0[j]     = (bf16)p[0][j];
            pa0[j + 4] = (bf16)p[1][j];
            pa1[j]     = (bf16)p[2][j];
            pa1[j + 4] = (bf16)p[3][j];
        }
        ol = __builtin_amdgcn_mfma_f32_16x16x32_bf16(pa0, vones, ol, 0, 0, 0);
        ol = __builtin_amdgcn_mfma_f32_16x16x32_bf16(pa1, vones, ol, 0, 0, 0);

        lgkm0();
        __builtin_amdgcn_s_setprio(1);
        #pragma unroll
        for (int dc = 0; dc < 4; ++dc)
            #pragma unroll
            for (int kk = 0; kk < 2; ++kk)
                o[dc] = __builtin_amdgcn_mfma_f32_16x16x32_bf16(kk ? pa1 : pa0, vbf[dc * 2 + kk], o[dc], 0, 0, 0);
        __builtin_amdgcn_s_setprio(0);
    };

    const int NU = qt + 1;
    stage(0, 0);
    asm volatile("" :: "v"(qf0), "v"(qf1));

    int u = 0;
    for (; u + 2 <= NU; u += 2) {
        bar();                              // close readers of buf1 (unit u-1)
        stage(u + 1, 1);
        vm_wait4();                         // stage(u) landed; stage(u+1) in flight
        bar();                              // publish buf0
        unit(kt, vtt, u * 64, false);       // u <= NU-2: never diagonal
        bar();                              // close readers of buf0
        bool hn = (u + 2 < NU);
        if (hn) { stage(u + 2, 0); vm_wait4(); } else vm_wait0();
        bar();                              // publish buf1
        unit(kt + 4096, vtt + 4096, (u + 1) * 64, (u + 1) == NU - 1);
    }
    if (u < NU) {                           // odd-NU tail: diagonal unit, buf0
        bar();
        vm_wait0();
        bar();
        unit(kt, vtt, u * 64, true);
    }

    // epilogue
    #pragma unroll
    for (int r = 0; r < 4; ++r) {
        float invl = 1.0f / ol[r];
        #pragma unroll
        for (int dc = 0; dc < 4; ++dc) {
            int row = qw + quad * 4 + r;
            int col = h * 64 + dc * 16 + l16;
            out[(size_t)(b * S_ + row) * 1024 + col] = (bf16)(o[dc][r] * invl);
        }
    }
}

// ---------------- launch ----------------
extern "C" void kernel_launch(void* const* d_in, const int* in_sizes, int n_in,
                              void* d_out, int out_size, void* d_ws, size_t ws_size,
                              hipStream_t stream) {
    const float* x  = (const float*)d_in[0];
    const float* wq = (const float*)d_in[1];
    const float* wk = (const float*)d_in[2];
    const float* wv = (const float*)d_in[3];
    const float* wo = (const float*)d_in[4];
    const float* fc = (const float*)d_in[5];
    const float* fs = (const float*)d_in[6];
    (void)in_sizes; (void)n_in; (void)out_size; (void)ws_size;

    char* ws = (char*)d_ws;
    bf16* xb    = (bf16*)(ws);                          // 16 MB, reused as q after GEMM1
    bf16* wqkvT = (bf16*)(ws + (16u << 20));            //  4 MB  [2048][1024]
    bf16* woT   = (bf16*)(ws + (20u << 20));            //  2 MB  [1024][1024]
    bf16* qkvb  = (bf16*)(ws + (22u << 20));            // 32 MB  [8192][2048], reused as attn out
    bf16* kb    = (bf16*)(ws + (54u << 20));            //  8 MB  [8][8][1024][64]
    bf16* vtb   = (bf16*)(ws + (62u << 20));            //  8 MB  [8][8][64][1024]  (70 MB total)
    bf16* qb    = xb;
    bf16* attnb = qkvb;

    k_prep1<<<dim3(8960), dim3(256), 0, stream>>>(x, wq, wk, wv, wo, xb, wqkvT, woT);

    // GEMM1: [8192,1024] x [2048,1024]^T -> 128x128 tiles, grid 16x64 = 1024 wgs (4 tile-slots/CU, 2 resident)
    k_gemm128<bf16><<<dim3(16, 64), dim3(256), 0, stream>>>(xb, wqkvT, qkvb, M_, 2048, 1024);

    k_prep2<<<dim3(9216), dim3(256), 0, stream>>>(qkvb, fc, fs, qb, kb, vtb);

    // attn: per-q-tile blocks, 2048 wgs, big tiles first
    k_attn<<<dim3(2048), dim3(256), 0, stream>>>(qb, kb, vtb, attnb);

    // GEMM2: [8192,1024] x [1024,1024]^T -> 128x128 tiles, grid 8x64 = 512 wgs
    k_gemm128<float><<<dim3(8, 64), dim3(256), 0, stream>>>(attnb, woT, (float*)d_out, M_, 1024, 1024);
}